// Round 1
// baseline (451.234 us; speedup 1.0000x reference)
//
#include <hip/hip_runtime.h>
#include <hip/hip_bf16.h>

#define H 1024
#define V 50257
#define L 50

// ---------------------------------------------------------------------------
// K1: attention — single block, 256 threads.
// scores[l] = attn_w[l,:] . [embedded, h0] + attn_b[l]; softmax; applied = w @ enc
// ---------------------------------------------------------------------------
__global__ void attn_kernel(const int* __restrict__ input_ids,
                            const float* __restrict__ hidden,
                            const float* __restrict__ enc,
                            const float* __restrict__ emb,
                            const float* __restrict__ attn_w,
                            const float* __restrict__ attn_b,
                            float* __restrict__ ws_emb,
                            float* __restrict__ ws_app,
                            float* __restrict__ out_attnw) {
    __shared__ __align__(16) float s_concat[2 * H];
    __shared__ float s_w[L];
    const int tid = threadIdx.x;           // 256
    const int token = input_ids[0];

    // load [embedded, h0] into LDS (float4), mirror embedded to ws
    const float4* e4 = (const float4*)(emb + (size_t)token * H);
    const float4* h4 = (const float4*)hidden;
    {
        float4 e = e4[tid];
        float4 h = h4[tid];
        ((float4*)s_concat)[tid] = e;
        ((float4*)(s_concat + H))[tid] = h;
        ((float4*)ws_emb)[tid] = e;
    }
    __syncthreads();

    const int wave = tid >> 6, lane = tid & 63;
    // scores: wave-per-row over L rows of length 2H (512 float4)
    for (int l = wave; l < L; l += 4) {
        const float4* r4 = (const float4*)(attn_w + (size_t)l * 2 * H);
        const float4* c4 = (const float4*)s_concat;
        float acc = 0.f;
        for (int k = lane; k < 512; k += 64) {
            float4 a = r4[k], b = c4[k];
            acc += a.x * b.x + a.y * b.y + a.z * b.z + a.w * b.w;
        }
        #pragma unroll
        for (int off = 32; off; off >>= 1) acc += __shfl_down(acc, off);
        if (lane == 0) s_w[l] = acc + attn_b[l];
    }
    __syncthreads();

    // softmax over 50 values (serial on thread 0 — trivial)
    if (tid == 0) {
        float m = s_w[0];
        for (int l = 1; l < L; ++l) m = fmaxf(m, s_w[l]);
        float s = 0.f;
        for (int l = 0; l < L; ++l) { s_w[l] = __expf(s_w[l] - m); s += s_w[l]; }
        float inv = 1.f / s;
        for (int l = 0; l < L; ++l) s_w[l] *= inv;
    }
    __syncthreads();
    if (tid < L) out_attnw[tid] = s_w[tid];

    // applied[j] = sum_l w[l] * enc[l][j]  — thread owns 4 consecutive j
    float4 acc = make_float4(0.f, 0.f, 0.f, 0.f);
    for (int l = 0; l < L; ++l) {
        float w = s_w[l];
        float4 v = ((const float4*)(enc + (size_t)l * H))[tid];
        acc.x += w * v.x; acc.y += w * v.y; acc.z += w * v.z; acc.w += w * v.w;
    }
    ((float4*)ws_app)[tid] = acc;
}

// ---------------------------------------------------------------------------
// K2: comb matvec (H rows x 2H) + relu.  grid 256 x 256, wave-per-row.
// ---------------------------------------------------------------------------
__global__ void comb_kernel(const float* __restrict__ comb_w,
                            const float* __restrict__ comb_b,
                            const float* __restrict__ embedded,
                            const float* __restrict__ applied,
                            float* __restrict__ x1) {
    __shared__ __align__(16) float s_c[2 * H];
    const int tid = threadIdx.x;
    ((float4*)s_c)[tid] = ((const float4*)embedded)[tid];
    ((float4*)(s_c + H))[tid] = ((const float4*)applied)[tid];
    __syncthreads();

    const int wave = tid >> 6, lane = tid & 63;
    const int i = blockIdx.x * 4 + wave;   // 0..1023
    const float4* r4 = (const float4*)(comb_w + (size_t)i * 2 * H);
    const float4* c4 = (const float4*)s_c;
    float acc = 0.f;
    for (int k = lane; k < 512; k += 64) {
        float4 a = r4[k], b = c4[k];
        acc += a.x * b.x + a.y * b.y + a.z * b.z + a.w * b.w;
    }
    #pragma unroll
    for (int off = 32; off; off >>= 1) acc += __shfl_down(acc, off);
    if (lane == 0) x1[i] = fmaxf(acc + comb_b[i], 0.f);
}

// ---------------------------------------------------------------------------
// K3/K4: GRU cell. Each wave owns output element i and computes all 6 dots
// (r,z,n for w_ih and w_hh) so the gate math needs no cross-block sync.
// grid 256 x 256 (4 waves/block -> 1024 rows).
// ---------------------------------------------------------------------------
__global__ void gru_kernel(const float* __restrict__ x,
                           const float* __restrict__ hprev,
                           const float* __restrict__ w_ih,
                           const float* __restrict__ w_hh,
                           const float* __restrict__ b_ih,
                           const float* __restrict__ b_hh,
                           float* __restrict__ h_out,
                           float* __restrict__ x_out,   // relu(h) for next layer, nullable
                           float* __restrict__ h_copy)  // mirror (d_out), nullable
{
    __shared__ __align__(16) float s_x[H];
    __shared__ __align__(16) float s_h[H];
    const int tid = threadIdx.x;
    ((float4*)s_x)[tid] = ((const float4*)x)[tid];
    ((float4*)s_h)[tid] = ((const float4*)hprev)[tid];
    __syncthreads();

    const int wave = tid >> 6, lane = tid & 63;
    const int i = blockIdx.x * 4 + wave;   // 0..1023
    const float4* x4 = (const float4*)s_x;
    const float4* h4 = (const float4*)s_h;
    const float4* wr_x = (const float4*)(w_ih + (size_t)i * H);
    const float4* wz_x = (const float4*)(w_ih + (size_t)(H + i) * H);
    const float4* wn_x = (const float4*)(w_ih + (size_t)(2 * H + i) * H);
    const float4* wr_h = (const float4*)(w_hh + (size_t)i * H);
    const float4* wz_h = (const float4*)(w_hh + (size_t)(H + i) * H);
    const float4* wn_h = (const float4*)(w_hh + (size_t)(2 * H + i) * H);

    float ar = 0.f, az = 0.f, an = 0.f, br = 0.f, bz = 0.f, bn = 0.f;
    for (int k = lane; k < 256; k += 64) {   // 1024 floats = 256 float4
        float4 xv = x4[k], hv = h4[k], t;
        t = wr_x[k]; ar += t.x * xv.x + t.y * xv.y + t.z * xv.z + t.w * xv.w;
        t = wz_x[k]; az += t.x * xv.x + t.y * xv.y + t.z * xv.z + t.w * xv.w;
        t = wn_x[k]; an += t.x * xv.x + t.y * xv.y + t.z * xv.z + t.w * xv.w;
        t = wr_h[k]; br += t.x * hv.x + t.y * hv.y + t.z * hv.z + t.w * hv.w;
        t = wz_h[k]; bz += t.x * hv.x + t.y * hv.y + t.z * hv.z + t.w * hv.w;
        t = wn_h[k]; bn += t.x * hv.x + t.y * hv.y + t.z * hv.z + t.w * hv.w;
    }
    #pragma unroll
    for (int off = 32; off; off >>= 1) {
        ar += __shfl_down(ar, off); az += __shfl_down(az, off);
        an += __shfl_down(an, off); br += __shfl_down(br, off);
        bz += __shfl_down(bz, off); bn += __shfl_down(bn, off);
    }
    if (lane == 0) {
        float gxr = ar + b_ih[i],         ghr = br + b_hh[i];
        float gxz = az + b_ih[H + i],     ghz = bz + b_hh[H + i];
        float gxn = an + b_ih[2 * H + i], ghn = bn + b_hh[2 * H + i];
        float r = 1.f / (1.f + expf(-(gxr + ghr)));
        float z = 1.f / (1.f + expf(-(gxz + ghz)));
        float n = tanhf(gxn + r * ghn);
        float hn = (1.f - z) * n + z * s_h[i];
        h_out[i] = hn;
        if (x_out) x_out[i] = fmaxf(hn, 0.f);
        if (h_copy) h_copy[i] = hn;
    }
}

// ---------------------------------------------------------------------------
// K5: vocab logits (V rows x H), wave-per-row, 8 rows/block (2 per wave).
// Also emits per-block partial sum of exp(logit) — deterministic reduce later.
// ---------------------------------------------------------------------------
__global__ void logits_kernel(const float* __restrict__ out_w,
                              const float* __restrict__ out_b,
                              const float* __restrict__ h,
                              float* __restrict__ logits,
                              float* __restrict__ partials) {
    __shared__ __align__(16) float s_h[H];
    __shared__ float s_part[4];
    const int tid = threadIdx.x;
    ((float4*)s_h)[tid] = ((const float4*)h)[tid];
    __syncthreads();

    const int wave = tid >> 6, lane = tid & 63;
    const float4* h4 = (const float4*)s_h;
    float psum = 0.f;
    #pragma unroll
    for (int rr = 0; rr < 2; ++rr) {
        const int v = blockIdx.x * 8 + wave * 2 + rr;
        if (v < V) {
            const float4* w4 = (const float4*)(out_w + (size_t)v * H);
            float acc = 0.f;
            for (int k = lane; k < 256; k += 64) {
                float4 a = w4[k], b = h4[k];
                acc += a.x * b.x + a.y * b.y + a.z * b.z + a.w * b.w;
            }
            #pragma unroll
            for (int off = 32; off; off >>= 1) acc += __shfl_down(acc, off);
            if (lane == 0) {
                float lg = acc + out_b[v];
                logits[v] = lg;
                psum += expf(lg);
            }
        }
    }
    if (lane == 0) s_part[wave] = psum;
    __syncthreads();
    if (tid == 0) partials[blockIdx.x] = s_part[0] + s_part[1] + s_part[2] + s_part[3];
}

// K6: reduce partial exp-sums -> log-sum-exp scalar (single block, deterministic)
__global__ void lse_kernel(const float* __restrict__ partials, int n,
                           float* __restrict__ lse) {
    __shared__ float red[256];
    const int tid = threadIdx.x;
    float s = 0.f;
    for (int i = tid; i < n; i += 256) s += partials[i];
    red[tid] = s;
    __syncthreads();
    for (int off = 128; off; off >>= 1) {
        if (tid < off) red[tid] += red[tid + off];
        __syncthreads();
    }
    if (tid == 0) *lse = logf(red[0]);
}

// K7: log_probs[v] = logits[v] - lse
__global__ void sub_kernel(const float* __restrict__ logits,
                           const float* __restrict__ lse,
                           float* __restrict__ out) {
    const int v = blockIdx.x * 256 + threadIdx.x;
    if (v < V) out[v] = logits[v] - *lse;
}

// ---------------------------------------------------------------------------
extern "C" void kernel_launch(void* const* d_in, const int* in_sizes, int n_in,
                              void* d_out, int out_size, void* d_ws, size_t ws_size,
                              hipStream_t stream) {
    const int*   input_ids = (const int*)d_in[0];
    const float* hidden    = (const float*)d_in[1];
    const float* enc       = (const float*)d_in[2];
    const float* emb       = (const float*)d_in[3];
    const float* attn_w    = (const float*)d_in[4];
    const float* attn_b    = (const float*)d_in[5];
    const float* comb_w    = (const float*)d_in[6];
    const float* comb_b    = (const float*)d_in[7];
    const float* w_ih      = (const float*)d_in[8];
    const float* w_hh      = (const float*)d_in[9];
    const float* b_ih      = (const float*)d_in[10];
    const float* b_hh      = (const float*)d_in[11];
    const float* out_w     = (const float*)d_in[12];
    const float* out_b     = (const float*)d_in[13];

    float* out = (float*)d_out;            // [V | H | L]
    float* ws  = (float*)d_ws;
    float* ws_emb    = ws;                 // H
    float* ws_app    = ws + 1024;          // H
    float* ws_x1     = ws + 2048;          // H
    float* ws_h1     = ws + 3072;          // H
    float* ws_x2     = ws + 4096;          // H
    float* ws_h2     = ws + 5120;          // H
    float* ws_logits = ws + 6144;          // V (padded region to 50432)
    float* ws_part   = ws + 6144 + 50432;  // 6283 partials
    float* ws_lse    = ws_part + 6400;     // scalar

    const int nblk_logits = (V + 7) / 8;   // 6283

    attn_kernel<<<1, 256, 0, stream>>>(input_ids, hidden, enc, emb, attn_w, attn_b,
                                       ws_emb, ws_app, out + V + H);
    comb_kernel<<<256, 256, 0, stream>>>(comb_w, comb_b, ws_emb, ws_app, ws_x1);
    gru_kernel<<<256, 256, 0, stream>>>(ws_x1, hidden, w_ih, w_hh, b_ih, b_hh,
                                        ws_h1, ws_x2, nullptr);
    gru_kernel<<<256, 256, 0, stream>>>(ws_x2, ws_h1, w_ih, w_hh, b_ih, b_hh,
                                        ws_h2, nullptr, out + V);
    logits_kernel<<<nblk_logits, 256, 0, stream>>>(out_w, out_b, ws_h2,
                                                   ws_logits, ws_part);
    lse_kernel<<<1, 256, 0, stream>>>(ws_part, nblk_logits, ws_lse);
    sub_kernel<<<(V + 255) / 256, 256, 0, stream>>>(ws_logits, ws_lse, out);
}